// Round 7
// baseline (1203.729 us; speedup 1.0000x reference)
//
#include <hip/hip_runtime.h>

// Problem constants (from reference)
constexpr int B_ = 8;
constexpr int N_ = 16384;
constexpr int NG = 512;     // NUM_GROUPS
constexpr int GS = 32;      // GROUP_SIZE
constexpr int KORIG = 160;  // K_ORIGINAL = 5*GROUP_SIZE
constexpr int TPB = 512;    // fps threads (8 waves)
constexpr int PPT = 32;     // points per thread, contiguous
#define R2 0.04f
#define RADIUS 0.2f

__device__ __forceinline__ unsigned f32_ord(float f) {
  unsigned u = __float_as_uint(f);
  return (u & 0x80000000u) ? ~u : (u | 0x80000000u);
}

// fmax with a DPP-permuted copy; ctrl must be an immediate -> template param
template <int CTRL>
__device__ __forceinline__ float dpp_fmax(float v) {
  int o = __builtin_amdgcn_update_dpp(0, __float_as_int(v), CTRL, 0xF, 0xF, true);
  return fmaxf(v, __int_as_float(o));
}
// full 64-lane max: xor1,xor2 (quad_perm), mirrors within 8/16, xor16, xor32
__device__ __forceinline__ float wave_fmax(float v) {
  v = dpp_fmax<0xB1>(v);   // quad_perm [1,0,3,2]
  v = dpp_fmax<0x4E>(v);   // quad_perm [2,3,0,1]
  v = dpp_fmax<0x141>(v);  // row_half_mirror (combines quads within 8)
  v = dpp_fmax<0x140>(v);  // row_mirror      (combines 8s within 16)
  v = fmaxf(v, __int_as_float(__builtin_amdgcn_ds_swizzle(__float_as_int(v), 0x401F)));  // xor16
  v = fmaxf(v, __shfl_xor(v, 32, 64));  // xor32
  return v;
}
// max within each 8-lane group (lanes 8g..8g+7 hold the 8 wave partials)
__device__ __forceinline__ float group8_fmax(float v) {
  v = dpp_fmax<0xB1>(v);
  v = dpp_fmax<0x4E>(v);
  v = dpp_fmax<0x141>(v);
  return v;
}

// ---------------- Kernel 1: farthest point sampling ----------------
// One block per batch, 512 threads (8 waves), thread t owns points [32t,32t+32)
// CONTIGUOUS: global index order == (wave, lane, j) order, so first-index
// argmax tie-break = lowest wave, lowest lane, lowest j.
// launch_bounds(512,2): VGPR cap 256 -> the 128-float working set stays in
// registers (round-6's VGPR=88 meant spill-to-scratch = the 2x slowdown).
// Value-only DPP reduces; ONLY the winning wave runs the coord-extraction
// chain (others skip via uniform branch); coords broadcast through LDS.
__global__ __launch_bounds__(512, 2) void fps_kernel(const float4* __restrict__ p4,
                                                     const int* __restrict__ lengths,
                                                     float* __restrict__ centers) {
#pragma clang fp contract(off)
  const int b = blockIdx.x;
  const int t = threadIdx.x;
  const int lane = t & 63;
  const int wid = t >> 6;
  const int len = lengths[b];
  const float4* bp = p4 + (size_t)b * N_;

  __shared__ float pubf[8];    // per-wave max
  __shared__ float4 cpub;      // winner coords

  float x[PPT], y[PPT], z[PPT], m[PPT];
#pragma unroll
  for (int j = 0; j < PPT; ++j) {
    const int i = t * PPT + j;
    float4 p = bp[i];
    x[j] = p.x; y[j] = p.y; z[j] = p.z;
    m[j] = (i < len) ? __builtin_inff() : -__builtin_inff();
  }

  float4 c0 = bp[0];  // reference scan starts at cur=0
  float cx = c0.x, cy = c0.y, cz = c0.z;
  if (t == 0) {
    size_t o = (size_t)b * NG * 3;
    centers[o] = cx; centers[o + 1] = cy; centers[o + 2] = cz;
  }

  for (int k = 0; k < NG - 1; ++k) {
    // --- mindist update: exact per-point formula (contract OFF) ---
#pragma unroll
    for (int j = 0; j < PPT; ++j) {
      float dx = x[j] - cx;
      float dy = y[j] - cy;
      float dz = z[j] - cz;
      float d = dx * dx + dy * dy + dz * dz;  // ((dx2+dy2)+dz2) = np.sum order
      m[j] = fminf(m[j], d);
    }
    // --- thread max: 31-op pairwise tree (v_max3-fusable) ---
    float u0 = fmaxf(m[0], m[1]),   u1 = fmaxf(m[2], m[3]);
    float u2 = fmaxf(m[4], m[5]),   u3 = fmaxf(m[6], m[7]);
    float u4 = fmaxf(m[8], m[9]),   u5 = fmaxf(m[10], m[11]);
    float u6 = fmaxf(m[12], m[13]), u7 = fmaxf(m[14], m[15]);
    float u8 = fmaxf(m[16], m[17]), u9 = fmaxf(m[18], m[19]);
    float uA = fmaxf(m[20], m[21]), uB = fmaxf(m[22], m[23]);
    float uC = fmaxf(m[24], m[25]), uD = fmaxf(m[26], m[27]);
    float uE = fmaxf(m[28], m[29]), uF = fmaxf(m[30], m[31]);
    float v0 = fmaxf(u0, u1), v1 = fmaxf(u2, u3), v2 = fmaxf(u4, u5), v3 = fmaxf(u6, u7);
    float v4 = fmaxf(u8, u9), v5 = fmaxf(uA, uB), v6 = fmaxf(uC, uD), v7 = fmaxf(uE, uF);
    float w0 = fmaxf(v0, v1), w1 = fmaxf(v2, v3), w2 = fmaxf(v4, v5), w3 = fmaxf(v6, v7);
    const float sm = fmaxf(fmaxf(w0, w1), fmaxf(w2, w3));

    // --- wave max (value only), publish per-wave partial ---
    const float wmax = wave_fmax(sm);
    if (lane == 0) pubf[wid] = wmax;
    __syncthreads();

    // --- cross-wave value max + winner wave id (all waves, cheap) ---
    const float pw = pubf[lane & 7];
    const float kmax = group8_fmax(pw);
    const unsigned long long bal = __ballot(pw == kmax);
    const int grp = lane & 56;
    const int ww = __ffsll((bal >> grp) & 0xFFull) - 1;  // lowest wave = lowest index

    // --- winner wave only: extract first-index coords, publish ---
    if (wid == ww) {
      float gx = x[0], gy = y[0], gz = z[0];
      bool fnd = (m[0] == kmax);
#pragma unroll
      for (int j = 1; j < PPT; ++j) {
        const bool sel = (m[j] == kmax) && !fnd;
        gx = sel ? x[j] : gx;
        gy = sel ? y[j] : gy;
        gz = sel ? z[j] : gz;
        fnd = fnd || sel;
      }
      const unsigned long long mb = __ballot(fnd);
      const int wl = __ffsll(mb) - 1;  // lowest lane = lowest index
      if (lane == wl) cpub = make_float4(gx, gy, gz, 0.0f);
    }
    __syncthreads();

    const float4 c = cpub;
    cx = c.x; cy = c.y; cz = c.z;
    if (t == 0) {
      size_t o = ((size_t)b * NG + (k + 1)) * 3;
      centers[o] = cx; centers[o + 1] = cy; centers[o + 2] = cz;
    }
  }
}

// ---------------- Kernel 2: ball query + energy top-k + gather ----------------
// One wave per (batch, group). Ordered compaction of first 160 in-ball indices,
// then 32 rounds of min-key extraction = top_k by (energy desc, index asc).
__global__ __launch_bounds__(64) void group_kernel(const float4* __restrict__ p4,
                                                   const int* __restrict__ lengths,
                                                   const float* __restrict__ centers,
                                                   float4* __restrict__ outg) {
#pragma clang fp contract(off)
  const int gid = blockIdx.x;
  const int b = gid >> 9;
  const int lane = threadIdx.x;
  const int len = lengths[b];
  const float4* bp = p4 + (size_t)b * N_;
  const float cx = centers[(size_t)gid * 3 + 0];
  const float cy = centers[(size_t)gid * 3 + 1];
  const float cz = centers[(size_t)gid * 3 + 2];

  __shared__ int cand[KORIG];
  int M = 0;  // wave-uniform running in-ball count
  for (int cb = 0; cb < N_ && M < KORIG; cb += 256) {
#pragma unroll
    for (int q = 0; q < 4; ++q) {
      const int i = cb + q * 64 + lane;
      float4 p = bp[i];
      float dx = p.x - cx;
      float dy = p.y - cy;
      float dz = p.z - cz;
      float d2 = dx * dx + dy * dy + dz * dz;  // contract OFF
      const bool pred = (i < len) && (d2 < R2);
      unsigned long long mb = __ballot(pred);
      if (pred) {
        int pos = M + (int)__popcll(mb & ((1ull << lane) - 1ull));
        if (pos < KORIG) cand[pos] = i;  // first-160-by-index semantics
      }
      M += (int)__popcll(mb);
    }
  }
  if (M > KORIG) M = KORIG;
  __syncthreads();

  // keys: (energy desc, index asc) -> ascending u64
  const unsigned long long SENT = ~0ull;
  unsigned long long key0 = SENT, key1 = SENT, key2 = SENT;
  {
    int c0 = lane, c1 = lane + 64, c2 = lane + 128;
    if (c0 < M) { int i = cand[c0]; key0 = ((unsigned long long)(~f32_ord(bp[i].w)) << 32) | (unsigned)i; }
    if (c1 < M) { int i = cand[c1]; key1 = ((unsigned long long)(~f32_ord(bp[i].w)) << 32) | (unsigned)i; }
    if (c2 < M) { int i = cand[c2]; key2 = ((unsigned long long)(~f32_ord(bp[i].w)) << 32) | (unsigned)i; }
  }

  int mysel = -1;  // lane j holds the j-th selected index
  for (int j = 0; j < GS; ++j) {
    unsigned long long kmin = key0 < key1 ? key0 : key1;
    if (key2 < kmin) kmin = key2;
#pragma unroll
    for (int off = 32; off > 0; off >>= 1) {
      unsigned long long o = __shfl_xor(kmin, off, 64);
      if (o < kmin) kmin = o;
    }
    if (kmin == SENT) break;  // fewer than 32 candidates; rest stay -1
    if (lane == j) mysel = (int)(unsigned)kmin;
    if (key0 == kmin) key0 = SENT;
    if (key1 == kmin) key1 = SENT;
    if (key2 == kmin) key2 = SENT;
  }

  const int first = __shfl(mysel, 0, 64);  // highest-energy candidate (or -1 if empty)
  if (lane < GS) {
    int idx = (mysel < 0) ? first : mysel;  // reference: -1 -> idx[:, :, :1]
    float4 o;
    if (idx >= 0) {
      float4 p = bp[idx];
      o.x = (p.x - cx) / RADIUS;
      o.y = (p.y - cy) / RADIUS;
      o.z = (p.z - cz) / RADIUS;
      o.w = p.w / RADIUS;
    } else {
      // masked_gather gives 0, then (0 - center)/radius
      o.x = (0.0f - cx) / RADIUS;
      o.y = (0.0f - cy) / RADIUS;
      o.z = (0.0f - cz) / RADIUS;
      o.w = 0.0f;
    }
    outg[(size_t)gid * GS + lane] = o;
  }
}

extern "C" void kernel_launch(void* const* d_in, const int* in_sizes, int n_in,
                              void* d_out, int out_size, void* d_ws, size_t ws_size,
                              hipStream_t stream) {
  const float4* pts = (const float4*)d_in[0];
  const int* lengths = (const int*)d_in[1];
  float* out = (float*)d_out;
  // out layout: groups (8,512,32,4) flat, then centers (8,512,3) flat
  float* centers = out + (size_t)B_ * NG * GS * 4;
  float4* groups = (float4*)out;

  fps_kernel<<<B_, TPB, 0, stream>>>(pts, lengths, centers);
  group_kernel<<<B_ * NG, 64, 0, stream>>>(pts, lengths, centers, groups);
}

// Round 8
// 974.263 us; speedup vs baseline: 1.2355x; 1.2355x over previous
//
#include <hip/hip_runtime.h>

// Problem constants (from reference)
constexpr int B_ = 8;
constexpr int N_ = 16384;
constexpr int NG = 512;     // NUM_GROUPS
constexpr int GS = 32;      // GROUP_SIZE
constexpr int KORIG = 160;  // K_ORIGINAL = 5*GROUP_SIZE
constexpr int TPB = 1024;   // fps threads (16 waves)
constexpr int PPT = 16;     // points per thread, contiguous ownership
#define R2 0.04f
#define RADIUS 0.2f

__device__ __forceinline__ unsigned f32_ord(float f) {
  unsigned u = __float_as_uint(f);
  return (u & 0x80000000u) ? ~u : (u | 0x80000000u);
}

// fmax with a DPP-permuted copy; ctrl must be an immediate -> template param
template <int CTRL>
__device__ __forceinline__ float dpp_fmax(float v) {
  int o = __builtin_amdgcn_update_dpp(0, __float_as_int(v), CTRL, 0xF, 0xF, true);
  return fmaxf(v, __int_as_float(o));
}
// full 64-lane max
__device__ __forceinline__ float wave_fmax(float v) {
  v = dpp_fmax<0xB1>(v);   // quad_perm [1,0,3,2]
  v = dpp_fmax<0x4E>(v);   // quad_perm [2,3,0,1]
  v = dpp_fmax<0x141>(v);  // row_half_mirror (within 8)
  v = dpp_fmax<0x140>(v);  // row_mirror      (within 16)
  v = fmaxf(v, __int_as_float(__builtin_amdgcn_ds_swizzle(__float_as_int(v), 0x401F)));  // xor16
  v = fmaxf(v, __shfl_xor(v, 32, 64));  // xor32
  return v;
}
// max within each 16-lane group (lanes g*16..g*16+15 hold the 16 wave partials)
__device__ __forceinline__ float group16_fmax(float v) {
  v = dpp_fmax<0xB1>(v);
  v = dpp_fmax<0x4E>(v);
  v = dpp_fmax<0x141>(v);
  v = dpp_fmax<0x140>(v);
  return v;
}

// ---------------- Kernel 1: farthest point sampling ----------------
// One block per batch, 1024 threads (16 waves); thread t owns points
// [16t, 16t+16) CONTIGUOUS (tie-break order = wave, lane, j = index order).
// KEY CHANGE vs r6/r7: x,y live in LDS (128 KiB), only z[16]+m[16] in regs
// (~80 live) — below the ~90 VGPRs the allocator empirically grants, so the
// per-iteration scratch/global rematerialization (the r6/r7 stall) is gone.
// LDS layout [wave][j][lane] float2: lane stride 8B = conflict-free.
__global__ __launch_bounds__(1024, 4) void fps_kernel(const float4* __restrict__ p4,
                                                      const int* __restrict__ lengths,
                                                      float* __restrict__ centers) {
#pragma clang fp contract(off)
  const int b = blockIdx.x;
  const int t = threadIdx.x;
  const int lane = t & 63;
  const int wid = t >> 6;
  const int len = lengths[b];
  const float4* bp = p4 + (size_t)b * N_;

  __shared__ float2 sxy[N_];   // 128 KiB: [wid][j][lane] = wid*1024 + j*64 + lane
  __shared__ float pubf[16];   // per-wave max
  __shared__ float4 cpub;      // winner coords

  const int mybase = wid * 1024 + lane;  // + j*64

  float z[PPT], m[PPT];
#pragma unroll
  for (int j = 0; j < PPT; ++j) {
    const int i = t * PPT + j;
    float4 p = bp[i];
    sxy[mybase + j * 64] = make_float2(p.x, p.y);
    z[j] = p.z;
    m[j] = (i < len) ? __builtin_inff() : -__builtin_inff();
  }
  __syncthreads();

  float4 c0 = bp[0];  // reference scan starts at cur=0
  float cx = c0.x, cy = c0.y, cz = c0.z;
  if (t == 0) {
    size_t o = (size_t)b * NG * 3;
    centers[o] = cx; centers[o + 1] = cy; centers[o + 2] = cz;
  }

  for (int k = 0; k < NG - 1; ++k) {
    // --- mindist update: exact per-point formula (contract OFF) ---
#pragma unroll
    for (int j = 0; j < PPT; ++j) {
      float2 xy = sxy[mybase + j * 64];  // own slot; static offset ds_read_b64
      float dx = xy.x - cx;
      float dy = xy.y - cy;
      float dz = z[j] - cz;
      float d = dx * dx + dy * dy + dz * dz;  // ((dx2+dy2)+dz2) = np.sum order
      m[j] = fminf(m[j], d);
    }
    // --- thread max: 15-op pairwise tree ---
    float u0 = fmaxf(m[0], m[1]),   u1 = fmaxf(m[2], m[3]);
    float u2 = fmaxf(m[4], m[5]),   u3 = fmaxf(m[6], m[7]);
    float u4 = fmaxf(m[8], m[9]),   u5 = fmaxf(m[10], m[11]);
    float u6 = fmaxf(m[12], m[13]), u7 = fmaxf(m[14], m[15]);
    float v0 = fmaxf(u0, u1), v1 = fmaxf(u2, u3);
    float v2 = fmaxf(u4, u5), v3 = fmaxf(u6, u7);
    const float sm = fmaxf(fmaxf(v0, v1), fmaxf(v2, v3));

    // --- wave max (value only), publish per-wave partial ---
    const float wmax = wave_fmax(sm);
    if (lane == 0) pubf[wid] = wmax;
    __syncthreads();

    // --- cross-wave value max + winner wave id (all waves, cheap) ---
    const float pw = pubf[lane & 15];
    const float kmax = group16_fmax(pw);
    const unsigned long long bal = __ballot(pw == kmax);
    const int grp = lane & 48;
    const int ww = __ffsll((bal >> grp) & 0xFFFFull) - 1;  // lowest wave wins

    // --- winner wave only: first-index coords, publish through LDS ---
    if (wid == ww) {
      int jsel = 0;
      float zs = z[0];
      bool fnd = (m[0] == kmax);
#pragma unroll
      for (int j = 1; j < PPT; ++j) {
        const bool sel = (m[j] == kmax) && !fnd;
        jsel = sel ? j : jsel;
        zs = sel ? z[j] : zs;
        fnd = fnd || sel;
      }
      const unsigned long long mb = __ballot(fnd);
      const int wl = __ffsll(mb) - 1;  // lowest lane = lowest index
      if (lane == wl) {
        float2 xy = sxy[mybase + jsel * 64];  // dynamic index -> LDS read
        cpub = make_float4(xy.x, xy.y, zs, 0.0f);
      }
    }
    __syncthreads();

    const float4 c = cpub;
    cx = c.x; cy = c.y; cz = c.z;
    if (t == 0) {
      size_t o = ((size_t)b * NG + (k + 1)) * 3;
      centers[o] = cx; centers[o + 1] = cy; centers[o + 2] = cz;
    }
  }
}

// ---------------- Kernel 2: ball query + energy top-k + gather ----------------
// One wave per (batch, group). Ordered compaction of first 160 in-ball indices,
// then 32 rounds of min-key extraction = top_k by (energy desc, index asc).
__global__ __launch_bounds__(64) void group_kernel(const float4* __restrict__ p4,
                                                   const int* __restrict__ lengths,
                                                   const float* __restrict__ centers,
                                                   float4* __restrict__ outg) {
#pragma clang fp contract(off)
  const int gid = blockIdx.x;
  const int b = gid >> 9;
  const int lane = threadIdx.x;
  const int len = lengths[b];
  const float4* bp = p4 + (size_t)b * N_;
  const float cx = centers[(size_t)gid * 3 + 0];
  const float cy = centers[(size_t)gid * 3 + 1];
  const float cz = centers[(size_t)gid * 3 + 2];

  __shared__ int cand[KORIG];
  int M = 0;  // wave-uniform running in-ball count
  for (int cb = 0; cb < N_ && M < KORIG; cb += 256) {
#pragma unroll
    for (int q = 0; q < 4; ++q) {
      const int i = cb + q * 64 + lane;
      float4 p = bp[i];
      float dx = p.x - cx;
      float dy = p.y - cy;
      float dz = p.z - cz;
      float d2 = dx * dx + dy * dy + dz * dz;  // contract OFF
      const bool pred = (i < len) && (d2 < R2);
      unsigned long long mb = __ballot(pred);
      if (pred) {
        int pos = M + (int)__popcll(mb & ((1ull << lane) - 1ull));
        if (pos < KORIG) cand[pos] = i;  // first-160-by-index semantics
      }
      M += (int)__popcll(mb);
    }
  }
  if (M > KORIG) M = KORIG;
  __syncthreads();

  // keys: (energy desc, index asc) -> ascending u64
  const unsigned long long SENT = ~0ull;
  unsigned long long key0 = SENT, key1 = SENT, key2 = SENT;
  {
    int c0 = lane, c1 = lane + 64, c2 = lane + 128;
    if (c0 < M) { int i = cand[c0]; key0 = ((unsigned long long)(~f32_ord(bp[i].w)) << 32) | (unsigned)i; }
    if (c1 < M) { int i = cand[c1]; key1 = ((unsigned long long)(~f32_ord(bp[i].w)) << 32) | (unsigned)i; }
    if (c2 < M) { int i = cand[c2]; key2 = ((unsigned long long)(~f32_ord(bp[i].w)) << 32) | (unsigned)i; }
  }

  int mysel = -1;  // lane j holds the j-th selected index
  for (int j = 0; j < GS; ++j) {
    unsigned long long kmin = key0 < key1 ? key0 : key1;
    if (key2 < kmin) kmin = key2;
#pragma unroll
    for (int off = 32; off > 0; off >>= 1) {
      unsigned long long o = __shfl_xor(kmin, off, 64);
      if (o < kmin) kmin = o;
    }
    if (kmin == SENT) break;  // fewer than 32 candidates; rest stay -1
    if (lane == j) mysel = (int)(unsigned)kmin;
    if (key0 == kmin) key0 = SENT;
    if (key1 == kmin) key1 = SENT;
    if (key2 == kmin) key2 = SENT;
  }

  const int first = __shfl(mysel, 0, 64);  // highest-energy candidate (or -1 if empty)
  if (lane < GS) {
    int idx = (mysel < 0) ? first : mysel;  // reference: -1 -> idx[:, :, :1]
    float4 o;
    if (idx >= 0) {
      float4 p = bp[idx];
      o.x = (p.x - cx) / RADIUS;
      o.y = (p.y - cy) / RADIUS;
      o.z = (p.z - cz) / RADIUS;
      o.w = p.w / RADIUS;
    } else {
      // masked_gather gives 0, then (0 - center)/radius
      o.x = (0.0f - cx) / RADIUS;
      o.y = (0.0f - cy) / RADIUS;
      o.z = (0.0f - cz) / RADIUS;
      o.w = 0.0f;
    }
    outg[(size_t)gid * GS + lane] = o;
  }
}

extern "C" void kernel_launch(void* const* d_in, const int* in_sizes, int n_in,
                              void* d_out, int out_size, void* d_ws, size_t ws_size,
                              hipStream_t stream) {
  const float4* pts = (const float4*)d_in[0];
  const int* lengths = (const int*)d_in[1];
  float* out = (float*)d_out;
  // out layout: groups (8,512,32,4) flat, then centers (8,512,3) flat
  float* centers = out + (size_t)B_ * NG * GS * 4;
  float4* groups = (float4*)out;

  fps_kernel<<<B_, TPB, 0, stream>>>(pts, lengths, centers);
  group_kernel<<<B_ * NG, 64, 0, stream>>>(pts, lengths, centers, groups);
}

// Round 9
// 906.143 us; speedup vs baseline: 1.3284x; 1.0752x over previous
//
#include <hip/hip_runtime.h>

// Problem constants (from reference)
constexpr int B_ = 8;
constexpr int N_ = 16384;
constexpr int NG = 512;     // NUM_GROUPS
constexpr int GS = 32;      // GROUP_SIZE
constexpr int KORIG = 160;  // K_ORIGINAL = 5*GROUP_SIZE
constexpr int TPB = 1024;   // fps threads (16 waves)
constexpr int PPT = 16;     // points per thread, contiguous ownership
#define R2 0.04f
#define RADIUS 0.2f

__device__ __forceinline__ unsigned f32_ord(float f) {
  unsigned u = __float_as_uint(f);
  return (u & 0x80000000u) ? ~u : (u | 0x80000000u);
}

// fmax with a DPP-permuted copy; ctrl must be an immediate -> template param
template <int CTRL>
__device__ __forceinline__ float dpp_fmax(float v) {
  int o = __builtin_amdgcn_update_dpp(0, __float_as_int(v), CTRL, 0xF, 0xF, true);
  return fmaxf(v, __int_as_float(o));
}
// full 64-lane max
__device__ __forceinline__ float wave_fmax(float v) {
  v = dpp_fmax<0xB1>(v);   // quad_perm [1,0,3,2]
  v = dpp_fmax<0x4E>(v);   // quad_perm [2,3,0,1]
  v = dpp_fmax<0x141>(v);  // row_half_mirror (within 8)
  v = dpp_fmax<0x140>(v);  // row_mirror      (within 16)
  v = fmaxf(v, __int_as_float(__builtin_amdgcn_ds_swizzle(__float_as_int(v), 0x401F)));  // xor16
  v = fmaxf(v, __shfl_xor(v, 32, 64));  // xor32
  return v;
}
// max within each 16-lane group (lanes g*16..g*16+15 hold the 16 wave partials)
__device__ __forceinline__ float group16_fmax(float v) {
  v = dpp_fmax<0xB1>(v);
  v = dpp_fmax<0x4E>(v);
  v = dpp_fmax<0x141>(v);
  v = dpp_fmax<0x140>(v);
  return v;
}

// ---------------- Kernel 1: farthest point sampling ----------------
// One block per batch, 1024 threads (16 waves); thread t owns points
// [16t,16t+16) CONTIGUOUS (tie-break order = wave, lane, j = index order).
// x,y in LDS (128 KiB), z+m in regs (~52 VGPR, no spill — r8-verified).
// SINGLE barrier per iteration (counting-barrier + parity slots = race-free):
// index extracted pre-barrier via 4-level descent of the existing max tree;
// winner coords via wave-uniform s_load of bp[nxt] (no 2nd barrier/broadcast).
__global__ __launch_bounds__(1024, 4) void fps_kernel(const float4* __restrict__ p4,
                                                      const int* __restrict__ lengths,
                                                      float* __restrict__ centers) {
#pragma clang fp contract(off)
  const int b = blockIdx.x;
  const int t = threadIdx.x;
  const int lane = t & 63;
  const int wid = t >> 6;
  const int len = lengths[b];
  const float4* bp = p4 + (size_t)b * N_;

  __shared__ float2 sxy[N_];      // 128 KiB: [wid][j][lane] = wid*1024 + j*64 + lane
  __shared__ float pubf[2][16];   // per-wave max, parity dbuf
  __shared__ int pubi[2][16];     // per-wave winner global index, parity dbuf

  const int mybase = wid * 1024 + lane;  // + j*64

  float z[PPT], m[PPT];
#pragma unroll
  for (int j = 0; j < PPT; ++j) {
    const int i = t * PPT + j;
    float4 p = bp[i];
    sxy[mybase + j * 64] = make_float2(p.x, p.y);
    z[j] = p.z;
    m[j] = (i < len) ? __builtin_inff() : -__builtin_inff();
  }
  __syncthreads();

  float4 c0 = bp[0];  // reference scan starts at cur=0
  float cx = c0.x, cy = c0.y, cz = c0.z;
  if (t == 0) {
    size_t o = (size_t)b * NG * 3;
    centers[o] = cx; centers[o + 1] = cy; centers[o + 2] = cz;
  }

  for (int k = 0; k < NG - 1; ++k) {
    // --- mindist update: exact per-point formula (contract OFF) ---
#pragma unroll
    for (int j = 0; j < PPT; ++j) {
      float2 xy = sxy[mybase + j * 64];  // own slot; static-offset ds_read_b64
      float dx = xy.x - cx;
      float dy = xy.y - cy;
      float dz = z[j] - cz;
      float d = dx * dx + dy * dy + dz * dz;  // ((dx2+dy2)+dz2) = np.sum order
      m[j] = fminf(m[j], d);
    }
    // --- thread max: pairwise tree (keep levels for the descent) ---
    float u0 = fmaxf(m[0], m[1]),   u1 = fmaxf(m[2], m[3]);
    float u2 = fmaxf(m[4], m[5]),   u3 = fmaxf(m[6], m[7]);
    float u4 = fmaxf(m[8], m[9]),   u5 = fmaxf(m[10], m[11]);
    float u6 = fmaxf(m[12], m[13]), u7 = fmaxf(m[14], m[15]);
    float v0 = fmaxf(u0, u1), v1 = fmaxf(u2, u3);
    float v2 = fmaxf(u4, u5), v3 = fmaxf(u6, u7);
    float w0 = fmaxf(v0, v1), w1 = fmaxf(v2, v3);
    const float sm = fmaxf(w0, w1);

    // --- first-j via tree descent (go left iff left-subtree max attains sm) ---
    const bool b3 = (w0 != sm);                    // 1 -> right half m[8..15]
    const float vL = b3 ? v2 : v0;
    const bool b2 = (vL != sm);
    const float uL = b3 ? (b2 ? u6 : u4) : (b2 ? u2 : u0);
    const bool b1 = (uL != sm);
    const int hi3 = ((int)b3 << 3) | ((int)b2 << 2) | ((int)b1 << 1);
    const float mL = (hi3 & 8) ? ((hi3 & 4) ? ((hi3 & 2) ? m[14] : m[12])
                                            : ((hi3 & 2) ? m[10] : m[8]))
                               : ((hi3 & 4) ? ((hi3 & 2) ? m[6] : m[4])
                                            : ((hi3 & 2) ? m[2] : m[0]));
    const bool b0 = (mL != sm);
    const int bj = hi3 | (int)b0;

    // --- wave max + first-lane tie-break; publish (value, index) ---
    const float wmax = wave_fmax(sm);
    const unsigned long long att = __ballot(sm == wmax);
    const int wl = __ffsll(att) - 1;  // lowest lane = lowest index
    if (lane == wl) {
      pubf[k & 1][wid] = wmax;
      pubi[k & 1][wid] = t * PPT + bj;
    }
    __syncthreads();  // the only barrier in the loop

    // --- all waves: cross-wave value max, first wave wins, index broadcast ---
    const float pw = pubf[k & 1][lane & 15];
    const float kmax = group16_fmax(pw);
    const unsigned long long bal = __ballot(pw == kmax);
    const int grp = lane & 48;
    const int ww = __ffsll((bal >> grp) & 0xFFFFull) - 1;  // lowest wave wins
    const int nxt = pubi[k & 1][ww];       // broadcast LDS read
    const int snxt = __builtin_amdgcn_readfirstlane(nxt);  // force SGPR -> s_load
    const float4 c = bp[snxt];             // wave-uniform, L2-hot
    cx = c.x; cy = c.y; cz = c.z;

    if (t == 0) {
      size_t o = ((size_t)b * NG + (k + 1)) * 3;
      centers[o] = cx; centers[o + 1] = cy; centers[o + 2] = cz;
    }
  }
}

// ---------------- Kernel 2: ball query + energy top-k + gather ----------------
// One wave per (batch, group). Ordered compaction of first 160 in-ball indices,
// then 32 rounds of min-key extraction = top_k by (energy desc, index asc).
__global__ __launch_bounds__(64) void group_kernel(const float4* __restrict__ p4,
                                                   const int* __restrict__ lengths,
                                                   const float* __restrict__ centers,
                                                   float4* __restrict__ outg) {
#pragma clang fp contract(off)
  const int gid = blockIdx.x;
  const int b = gid >> 9;
  const int lane = threadIdx.x;
  const int len = lengths[b];
  const float4* bp = p4 + (size_t)b * N_;
  const float cx = centers[(size_t)gid * 3 + 0];
  const float cy = centers[(size_t)gid * 3 + 1];
  const float cz = centers[(size_t)gid * 3 + 2];

  __shared__ int cand[KORIG];
  int M = 0;  // wave-uniform running in-ball count
  for (int cb = 0; cb < N_ && M < KORIG; cb += 256) {
#pragma unroll
    for (int q = 0; q < 4; ++q) {
      const int i = cb + q * 64 + lane;
      float4 p = bp[i];
      float dx = p.x - cx;
      float dy = p.y - cy;
      float dz = p.z - cz;
      float d2 = dx * dx + dy * dy + dz * dz;  // contract OFF
      const bool pred = (i < len) && (d2 < R2);
      unsigned long long mb = __ballot(pred);
      if (pred) {
        int pos = M + (int)__popcll(mb & ((1ull << lane) - 1ull));
        if (pos < KORIG) cand[pos] = i;  // first-160-by-index semantics
      }
      M += (int)__popcll(mb);
    }
  }
  if (M > KORIG) M = KORIG;
  __syncthreads();

  // keys: (energy desc, index asc) -> ascending u64
  const unsigned long long SENT = ~0ull;
  unsigned long long key0 = SENT, key1 = SENT, key2 = SENT;
  {
    int c0 = lane, c1 = lane + 64, c2 = lane + 128;
    if (c0 < M) { int i = cand[c0]; key0 = ((unsigned long long)(~f32_ord(bp[i].w)) << 32) | (unsigned)i; }
    if (c1 < M) { int i = cand[c1]; key1 = ((unsigned long long)(~f32_ord(bp[i].w)) << 32) | (unsigned)i; }
    if (c2 < M) { int i = cand[c2]; key2 = ((unsigned long long)(~f32_ord(bp[i].w)) << 32) | (unsigned)i; }
  }

  int mysel = -1;  // lane j holds the j-th selected index
  for (int j = 0; j < GS; ++j) {
    unsigned long long kmin = key0 < key1 ? key0 : key1;
    if (key2 < kmin) kmin = key2;
#pragma unroll
    for (int off = 32; off > 0; off >>= 1) {
      unsigned long long o = __shfl_xor(kmin, off, 64);
      if (o < kmin) kmin = o;
    }
    if (kmin == SENT) break;  // fewer than 32 candidates; rest stay -1
    if (lane == j) mysel = (int)(unsigned)kmin;
    if (key0 == kmin) key0 = SENT;
    if (key1 == kmin) key1 = SENT;
    if (key2 == kmin) key2 = SENT;
  }

  const int first = __shfl(mysel, 0, 64);  // highest-energy candidate (or -1 if empty)
  if (lane < GS) {
    int idx = (mysel < 0) ? first : mysel;  // reference: -1 -> idx[:, :, :1]
    float4 o;
    if (idx >= 0) {
      float4 p = bp[idx];
      o.x = (p.x - cx) / RADIUS;
      o.y = (p.y - cy) / RADIUS;
      o.z = (p.z - cz) / RADIUS;
      o.w = p.w / RADIUS;
    } else {
      // masked_gather gives 0, then (0 - center)/radius
      o.x = (0.0f - cx) / RADIUS;
      o.y = (0.0f - cy) / RADIUS;
      o.z = (0.0f - cz) / RADIUS;
      o.w = 0.0f;
    }
    outg[(size_t)gid * GS + lane] = o;
  }
}

extern "C" void kernel_launch(void* const* d_in, const int* in_sizes, int n_in,
                              void* d_out, int out_size, void* d_ws, size_t ws_size,
                              hipStream_t stream) {
  const float4* pts = (const float4*)d_in[0];
  const int* lengths = (const int*)d_in[1];
  float* out = (float*)d_out;
  // out layout: groups (8,512,32,4) flat, then centers (8,512,3) flat
  float* centers = out + (size_t)B_ * NG * GS * 4;
  float4* groups = (float4*)out;

  fps_kernel<<<B_, TPB, 0, stream>>>(pts, lengths, centers);
  group_kernel<<<B_ * NG, 64, 0, stream>>>(pts, lengths, centers, groups);
}